// Round 1
// baseline (6120.971 us; speedup 1.0000x reference)
//
#include <hip/hip_runtime.h>
#include <cstddef>

// ---- problem constants ----
constexpr int Nn  = 100000;
constexpr int Dd  = 128;
constexpr int Aa  = 3;
constexpr int Pp  = 50000;
constexpr int Ee  = 500000;
constexpr int EFf = 500000;
constexpr int REG = Nn + 1;        // 100001 (count slots per CSR, incl. pad)
constexpr int NCSR = 7;            // 3x agg1(dst), 3x agg2(src), 1x family
constexpr int T7  = NCSR * REG;    // 700007
constexpr int RCH = 8;             // rows per LDS chunk in GEMM kernels

// =================== CSR build ===================
__global__ void k_invpop(const int* __restrict__ pop, int* __restrict__ invpop){
  int p = blockIdx.x*256 + threadIdx.x;
  if(p < Pp) invpop[pop[p]] = p;
}

__global__ void k_count(const int* __restrict__ eia, const int* __restrict__ fam,
                        int* __restrict__ cnt){
  int tid = blockIdx.x*256 + threadIdx.x;
  if(tid >= NCSR*Ee) return;
  int c = tid / Ee, e = tid - c*Ee;
  const int* key;
  if(c < 3)       key = eia + (c*2+1)*Ee;        // agg1: segment by dst
  else if(c < 6)  key = eia + ((c-3)*2)*Ee;      // agg2: segment by src
  else            key = fam;                      // agg3: segment by fam[0]
  atomicAdd(&cnt[c*REG + key[e]], 1);
}

__global__ void k_fill(const int* __restrict__ eia, const int* __restrict__ fam,
                       int* __restrict__ cursor, int* __restrict__ ebuf){
  int tid = blockIdx.x*256 + threadIdx.x;
  if(tid >= NCSR*Ee) return;
  int c = tid / Ee, e = tid - c*Ee;
  const int *key, *val;
  if(c < 3){      key = eia + (c*2+1)*Ee;      val = eia + (c*2)*Ee; }
  else if(c < 6){ key = eia + ((c-3)*2)*Ee;    val = eia + ((c-3)*2+1)*Ee; }
  else {          key = fam;                   val = fam + EFf; }
  int pos = atomicAdd(&cursor[c*REG + key[e]], 1);
  ebuf[pos] = val[e];
}

// ---- batched exclusive scan over the 7 concatenated count arrays ----
__global__ void k_scan_p1(const int* __restrict__ cnt, int* __restrict__ part){
  int b = blockIdx.x;
  int base = b*1024 + threadIdx.x*4;
  int s = 0;
  #pragma unroll
  for(int j=0;j<4;j++){ int idx=base+j; if(idx<T7) s += cnt[idx]; }
  __shared__ int red[256];
  red[threadIdx.x]=s; __syncthreads();
  for(int off=128; off>0; off>>=1){
    if(threadIdx.x<off) red[threadIdx.x]+=red[threadIdx.x+off];
    __syncthreads();
  }
  if(threadIdx.x==0) part[b]=red[0];
}

__global__ void k_scan_p2(int* __restrict__ part, int nchunks){
  __shared__ int buf[256];
  int t = threadIdx.x;
  int carry = 0;
  for(int base=0; base<nchunks; base+=256){
    int i = base+t;
    int v = (i<nchunks)? part[i] : 0;
    buf[t]=v; __syncthreads();
    for(int off=1; off<256; off<<=1){
      int add = (t>=off)? buf[t-off] : 0;
      __syncthreads();
      buf[t]+=add; __syncthreads();
    }
    if(i<nchunks) part[i] = carry + buf[t] - v;   // exclusive
    carry += buf[255];
    __syncthreads();
  }
}

__global__ void k_scan_p3(const int* __restrict__ cnt, const int* __restrict__ part,
                          int* __restrict__ offs, int* __restrict__ cursor){
  int b = blockIdx.x;
  int t = threadIdx.x;
  int idx0 = b*1024 + t*4;
  int v[4]; int s=0;
  #pragma unroll
  for(int j=0;j<4;j++){ int idx=idx0+j; v[j] = (idx<T7)? cnt[idx] : 0; s += v[j]; }
  __shared__ int buf[256];
  buf[t]=s; __syncthreads();
  for(int off=1; off<256; off<<=1){
    int add = (t>=off)? buf[t-off] : 0;
    __syncthreads();
    buf[t]+=add; __syncthreads();
  }
  int excl = buf[t] - s + part[b];
  #pragma unroll
  for(int j=0;j<4;j++){
    int idx=idx0+j;
    if(idx<T7){ offs[idx]=excl; cursor[idx]=excl; }
    excl += v[j];
  }
}

// =================== f64 Gauss-Jordan inverse of proj[a], M = inv+I ===================
__global__ void k_minit(const float* __restrict__ proj, double* __restrict__ W){
  int idx = blockIdx.x*256 + threadIdx.x;
  if(idx >= Aa*128*256) return;
  int a = idx/(128*256); int rem = idx - a*128*256;
  int i = rem/256, c = rem - i*256;
  double v;
  if(c<128) v = (double)proj[((size_t)a*128+i)*128 + c];
  else      v = (i == c-128) ? 1.0 : 0.0;
  W[idx]=v;
}

__global__ void k_gj(double* __restrict__ Wg, float* __restrict__ Mf32){
  int a = blockIdx.x;
  double* W = Wg + (size_t)a*128*256;
  int t = threadIdx.x;
  __shared__ double pv[128];
  __shared__ double smax[128];
  __shared__ int    sidx[128];
  for(int k=0;k<128;k++){
    if(t<128){
      double m=-1.0; int mi=k;
      if(t>=k){ m = fabs(W[(size_t)t*256+k]); mi=t; }
      smax[t]=m; sidx[t]=mi;
    }
    __syncthreads();
    for(int off=64; off>0; off>>=1){
      if(t<off){ if(smax[t+off]>smax[t]){ smax[t]=smax[t+off]; sidx[t]=sidx[t+off]; } }
      __syncthreads();
    }
    int pr = sidx[0];
    double pivot = W[(size_t)pr*256+k];
    __syncthreads();
    {
      double inv = 1.0/pivot;
      double vk = W[(size_t)k*256+t];
      double vp = W[(size_t)pr*256+t];
      W[(size_t)k*256+t] = vp*inv;
      if(pr!=k) W[(size_t)pr*256+t]=vk;
    }
    __syncthreads();
    if(t<128) pv[t] = W[(size_t)t*256+k];
    __syncthreads();
    double wk = W[(size_t)k*256+t];
    for(int r=0;r<128;r++){
      if(r==k) continue;
      W[(size_t)r*256+t] -= pv[r]*wk;
    }
    __syncthreads();
  }
  for(int idx=t; idx<128*128; idx+=256){
    int i=idx>>7, o=idx&127;
    double v = W[(size_t)i*256+128+o] + ((i==o)?1.0:0.0);
    Mf32[((size_t)a*128+i)*128+o] = (float)v;
  }
}

// =================== weights-in-registers GEMV/GEMM ===================
// MODE 0: esf  = pos[p,a,:] @ proj[a]                    (W [i,o])
// MODE 1: h    = relu([xattr[a,pop[p]], esf] @ aggW^T+b) (W [o,i], 256 i)
// MODE 2: xatt2= agg1@Wl1^T + xatt1@Wr1^T + b_l1         (dual, [o,i])
// MODE 3: upd  = relu(xatt2[a,pop[p]] @ M[a]), in-place  (W [i,o])
// MODE 4: attO = agg2@Wl2^T + xatt2@Wr2^T + b_l2, in-place over agg2
// MODE 5: indO = agg3@Wl3^T + xind@Wr3^T + b_l3, in-place over agg3
template<int MODE>
__launch_bounds__(256)
__global__ void k_gemm(const float* p1, const float* p2, const float* p3,
                       const float* __restrict__ w1p, const float* __restrict__ w2p,
                       const float* __restrict__ biasp,
                       const int* __restrict__ pop, const int* __restrict__ invpop,
                       float* out, int BPA)
{
  constexpr bool NEEDX2 = (MODE==1 || MODE==2 || MODE==4 || MODE==5);
  const int RPA = (MODE==0||MODE==1||MODE==3) ? Pp : Nn;
  const int a    = (MODE==5) ? 0 : (blockIdx.x / BPA);
  const int bidx = (MODE==5) ? blockIdx.x : (blockIdx.x - a*BPA);

  const int t = threadIdx.x;
  const int wave = t >> 6;
  const int lane = t & 63;
  const int o  = wave*32 + (lane>>1);
  const int ih = lane & 1;            // which half of the i-range this lane covers

  // ---- per-lane weight registers ----
  float4 w1v[16]; float4 w2v[16];
  if constexpr(MODE==0 || MODE==3){
    const float* W = w1p + (size_t)a*Dd*Dd;   // [i][o]
    #pragma unroll
    for(int jj=0;jj<16;jj++){
      int i0 = ih*64 + jj*4;
      float4 v;
      v.x = W[(size_t)(i0+0)*Dd + o];
      v.y = W[(size_t)(i0+1)*Dd + o];
      v.z = W[(size_t)(i0+2)*Dd + o];
      v.w = W[(size_t)(i0+3)*Dd + o];
      w1v[jj]=v;
    }
  } else if constexpr(MODE==1){
    const float* b1 = w1p + (size_t)o*256 + ih*64;       // aggW[o, 0:128]
    const float* b2 = b1 + 128;                          // aggW[o, 128:256]
    #pragma unroll
    for(int jj=0;jj<16;jj++){
      w1v[jj] = reinterpret_cast<const float4*>(b1)[jj];
      w2v[jj] = reinterpret_cast<const float4*>(b2)[jj];
    }
  } else {
    const size_t ao = (MODE==5)? (size_t)0 : (size_t)a*Dd*Dd;
    const float* W1 = w1p + ao + (size_t)o*Dd + ih*64;
    const float* W2 = w2p + ao + (size_t)o*Dd + ih*64;
    #pragma unroll
    for(int jj=0;jj<16;jj++){
      w1v[jj] = reinterpret_cast<const float4*>(W1)[jj];
      w2v[jj] = reinterpret_cast<const float4*>(W2)[jj];
    }
  }
  float bval = 0.f;
  if constexpr(MODE==1 || MODE==5) bval = biasp[o];
  else if constexpr(MODE==2 || MODE==4) bval = biasp[a*Dd + o];

  __shared__ float xs1[RCH][Dd];
  __shared__ float xs2[NEEDX2 ? RCH : 1][Dd];

  const int chunks = (RPA + RCH - 1)/RCH;
  for(int ch = bidx; ch < chunks; ch += BPA){
    const int r0 = ch*RCH;
    const int nr = min(RCH, RPA - r0);
    { // stage rows to LDS (one float4 per thread per stream)
      int r = t >> 5;
      int q = t & 31;
      if(r < nr){
        int row = r0 + r;
        const float* s1 = nullptr; const float* s2 = nullptr;
        if constexpr(MODE==0){ s1 = p1 + ((size_t)row*Aa + a)*Dd; }
        else if constexpr(MODE==1){
          s1 = p1 + ((size_t)a*Nn + pop[row])*Dd;
          s2 = p3 + ((size_t)a*Pp + row)*Dd;
        }
        else if constexpr(MODE==2){
          s1 = p1 + ((size_t)a*Nn + row)*Dd;
          int ip = invpop[row];
          s2 = (ip>=0) ? (p2 + ((size_t)a*Pp + ip)*Dd)
                       : (p3 + ((size_t)a*Nn + row)*Dd);
        }
        else if constexpr(MODE==3){ s1 = p1 + ((size_t)a*Nn + pop[row])*Dd; }
        else if constexpr(MODE==4){
          s1 = p1 + ((size_t)a*Nn + row)*Dd;
          s2 = p3 + ((size_t)a*Nn + row)*Dd;
        }
        else { s1 = p1 + (size_t)row*Dd; s2 = p3 + (size_t)row*Dd; }
        reinterpret_cast<float4*>(xs1[r])[q] = reinterpret_cast<const float4*>(s1)[q];
        if constexpr(NEEDX2)
          reinterpret_cast<float4*>(xs2[r])[q] = reinterpret_cast<const float4*>(s2)[q];
      }
    }
    __syncthreads();
    for(int r=0;r<nr;r++){
      float acc = 0.f;
      const float4* x1 = reinterpret_cast<const float4*>(xs1[r]) + ih*16;
      #pragma unroll
      for(int jj=0;jj<16;jj++){
        float4 xv = x1[jj]; float4 wv = w1v[jj];
        acc = fmaf(xv.x,wv.x,acc); acc = fmaf(xv.y,wv.y,acc);
        acc = fmaf(xv.z,wv.z,acc); acc = fmaf(xv.w,wv.w,acc);
      }
      if constexpr(NEEDX2){
        const float4* x2 = reinterpret_cast<const float4*>(xs2[r]) + ih*16;
        #pragma unroll
        for(int jj=0;jj<16;jj++){
          float4 xv = x2[jj]; float4 wv = w2v[jj];
          acc = fmaf(xv.x,wv.x,acc); acc = fmaf(xv.y,wv.y,acc);
          acc = fmaf(xv.z,wv.z,acc); acc = fmaf(xv.w,wv.w,acc);
        }
      }
      acc += __shfl_xor(acc, 1, 64);
      if(ih==0){
        float vout = acc;
        if constexpr(MODE==1 || MODE==2 || MODE==4 || MODE==5) vout += bval;
        if constexpr(MODE==1 || MODE==3) vout = fmaxf(vout, 0.f);
        int row = r0 + r;
        size_t orow;
        if constexpr(MODE==0)      orow = (size_t)a*Pp + row;
        else if constexpr(MODE==1) orow = (size_t)a*Pp + row;
        else if constexpr(MODE==2) orow = (size_t)a*Nn + row;
        else if constexpr(MODE==3) orow = (size_t)a*Nn + pop[row];
        else if constexpr(MODE==4) orow = (size_t)a*Nn + row;
        else                       orow = (size_t)row;
        out[orow*Dd + o] = vout;
      }
    }
    __syncthreads();
  }
}

// =================== CSR gather segment-mean (one wave per row) ===================
// WHICH 0: agg1 (src=x_individuals, regions 0..2, dst per-a)
// WHICH 1: agg2 (src=xatt2 per-a, regions 3..5, dst per-a)
// WHICH 2: agg3 (src=x_individuals, region 6, dst single)
template<int WHICH>
__global__ void k_seg(const float* __restrict__ src, const int* __restrict__ offs,
                      const int* __restrict__ ebuf, float* __restrict__ dst)
{
  const int nw = gridDim.x * 4;              // 256 threads = 4 waves per block
  int gw = (blockIdx.x*256 + threadIdx.x) >> 6;
  const int lane = threadIdx.x & 63;
  const int ROWS = (WHICH==2) ? Nn : Aa*Nn;
  const int cbase = (WHICH==0)?0 : (WHICH==1)?3 : 6;
  for(int row = gw; row < ROWS; row += nw){
    int aa = (WHICH==2)? 0   : row / Nn;
    int n  = (WHICH==2)? row : row - aa*Nn;
    const int* op = offs + (size_t)(cbase+aa)*REG + n;
    int s = op[0], e = op[1];
    float a0=0.f, a1=0.f;
    for(int j=s;j<e;++j){
      int v = ebuf[j];
      const float* rp = src + ((WHICH==1)? ((size_t)aa*Nn+v) : (size_t)v)*Dd;
      a0 += rp[lane]; a1 += rp[lane+64];
    }
    float sc = (e>s)? 1.f/(float)(e-s) : 0.f;
    float* dp = dst + ((WHICH==2)? (size_t)n : ((size_t)aa*Nn+n))*Dd;
    dp[lane]      = a0*sc;
    dp[lane+64]   = a1*sc;
  }
}

// =================== launch ===================
extern "C" void kernel_launch(void* const* d_in, const int* in_sizes, int n_in,
                              void* d_out, int out_size, void* d_ws, size_t ws_size,
                              hipStream_t stream)
{
  const float* xind  = (const float*)d_in[0];
  const float* xattr = (const float*)d_in[1];
  const float* posf  = (const float*)d_in[2];
  const int*   pop   = (const int*)  d_in[3];
  const int*   eia   = (const int*)  d_in[4];
  const int*   fam   = (const int*)  d_in[5];
  const float* proj  = (const float*)d_in[6];
  const float* aggW  = (const float*)d_in[7];
  const float* aggb  = (const float*)d_in[8];
  const float* Wl1   = (const float*)d_in[9];
  const float* bl1   = (const float*)d_in[10];
  const float* Wr1   = (const float*)d_in[11];
  const float* Wl2   = (const float*)d_in[12];
  const float* bl2   = (const float*)d_in[13];
  const float* Wr2   = (const float*)d_in[14];
  const float* Wl3   = (const float*)d_in[15];
  const float* bl3   = (const float*)d_in[16];
  const float* Wr3   = (const float*)d_in[17];

  float* outind = (float*)d_out;                     // (N,D)
  float* outatt = outind + (size_t)Nn*Dd;            // (A,N,D)

  // ---- workspace carve-up (~331 MB) ----
  float* h_buf   = (float*)d_ws;                         // A*P*D
  float* esf_buf = h_buf   + (size_t)Aa*Pp*Dd;           // A*P*D
  float* xatt2   = esf_buf + (size_t)Aa*Pp*Dd;           // A*N*D
  int*   ebuf    = (int*)(xatt2 + (size_t)Aa*Nn*Dd);     // 7E
  int*   cnt     = ebuf   + (size_t)NCSR*Ee;             // 700008 (padded)
  int*   offs    = cnt    + 700008;
  int*   cursor  = offs   + 700008;
  int*   part    = cursor + 700008;                      // 1024
  int*   invpop  = part   + 1024;                        // N
  double* Wgj    = (double*)(invpop + Nn);               // A*128*256 f64
  float*  Mf32   = (float*)(Wgj + (size_t)Aa*128*256);   // A*128*128

  hipMemsetAsync(cnt,    0,    sizeof(int)*700008, stream);
  hipMemsetAsync(invpop, 0xFF, sizeof(int)*Nn,     stream);

  k_invpop<<<(Pp+255)/256, 256, 0, stream>>>(pop, invpop);
  const int egrid = (NCSR*Ee + 255)/256;
  k_count<<<egrid, 256, 0, stream>>>(eia, fam, cnt);
  const int nchunks = (T7 + 1023)/1024;   // 684
  k_scan_p1<<<nchunks, 256, 0, stream>>>(cnt, part);
  k_scan_p2<<<1, 256, 0, stream>>>(part, nchunks);
  k_scan_p3<<<nchunks, 256, 0, stream>>>(cnt, part, offs, cursor);
  k_fill<<<egrid, 256, 0, stream>>>(eia, fam, cursor, ebuf);

  k_minit<<<(Aa*128*256+255)/256, 256, 0, stream>>>(proj, Wgj);
  k_gj<<<Aa, 256, 0, stream>>>(Wgj, Mf32);

  const int BPA = 240;
  // esf = pos @ proj
  k_gemm<0><<<Aa*BPA, 256, 0, stream>>>(posf, nullptr, nullptr,
                                        proj, nullptr, nullptr,
                                        pop, invpop, esf_buf, BPA);
  // h = relu([xattr[:,pop,:], esf] @ aggW^T + b)
  k_gemm<1><<<Aa*BPA, 256, 0, stream>>>(xattr, nullptr, esf_buf,
                                        aggW, nullptr, aggb,
                                        pop, invpop, h_buf, BPA);
  // agg1 -> outatt
  k_seg<0><<<1024, 256, 0, stream>>>(xind, offs, ebuf, outatt);
  // xatt2 = agg1@Wl1^T + xatt1@Wr1^T + b_l1   (xatt1 = xattr w/ pop rows = h)
  k_gemm<2><<<Aa*BPA, 256, 0, stream>>>(outatt, h_buf, xattr,
                                        Wl1, Wr1, bl1,
                                        pop, invpop, xatt2, BPA);
  // upd = relu(xatt2[:,pop,:] @ M), in place
  k_gemm<3><<<Aa*BPA, 256, 0, stream>>>(xatt2, nullptr, nullptr,
                                        Mf32, nullptr, nullptr,
                                        pop, invpop, xatt2, BPA);
  // agg2 -> outatt (overwrites agg1, which is dead)
  k_seg<1><<<1024, 256, 0, stream>>>(xatt2, offs, ebuf, outatt);
  // x_att_out = agg2@Wl2^T + xatt2@Wr2^T + b_l2, in place over agg2
  k_gemm<4><<<Aa*BPA, 256, 0, stream>>>(outatt, nullptr, xatt2,
                                        Wl2, Wr2, bl2,
                                        pop, invpop, outatt, BPA);
  // agg3 -> outind
  k_seg<2><<<1024, 256, 0, stream>>>(xind, offs, ebuf, outind);
  // x_ind_out = agg3@Wl3^T + xind@Wr3^T + b_l3, in place over agg3
  k_gemm<5><<<Aa*BPA, 256, 0, stream>>>(outind, nullptr, xind,
                                        Wl3, Wr3, bl3,
                                        pop, invpop, outind, Aa*BPA);
}

// Round 2
// 3849.085 us; speedup vs baseline: 1.5902x; 1.5902x over previous
//
#include <hip/hip_runtime.h>
#include <cstddef>

// ---- problem constants ----
constexpr int Nn  = 100000;
constexpr int Dd  = 128;
constexpr int Aa  = 3;
constexpr int Pp  = 50000;
constexpr int Ee  = 500000;
constexpr int EFf = 500000;
constexpr int REG = Nn + 1;        // 100001 (count slots per CSR, incl. pad)
constexpr int NCSR = 7;            // 3x agg1(dst), 3x agg2(src), 1x family
constexpr int T7  = NCSR * REG;    // 700007
constexpr int RCH = 8;             // rows per LDS chunk in GEMM kernels

// =================== CSR build ===================
__global__ void k_invpop(const int* __restrict__ pop, int* __restrict__ invpop){
  int p = blockIdx.x*256 + threadIdx.x;
  if(p < Pp) invpop[pop[p]] = p;
}

__global__ void k_count(const int* __restrict__ eia, const int* __restrict__ fam,
                        int* __restrict__ cnt){
  int tid = blockIdx.x*256 + threadIdx.x;
  if(tid >= NCSR*Ee) return;
  int c = tid / Ee, e = tid - c*Ee;
  const int* key;
  if(c < 3)       key = eia + (c*2+1)*Ee;        // agg1: segment by dst
  else if(c < 6)  key = eia + ((c-3)*2)*Ee;      // agg2: segment by src
  else            key = fam;                      // agg3: segment by fam[0]
  atomicAdd(&cnt[c*REG + key[e]], 1);
}

__global__ void k_fill(const int* __restrict__ eia, const int* __restrict__ fam,
                       int* __restrict__ cursor, int* __restrict__ ebuf){
  int tid = blockIdx.x*256 + threadIdx.x;
  if(tid >= NCSR*Ee) return;
  int c = tid / Ee, e = tid - c*Ee;
  const int *key, *val;
  if(c < 3){      key = eia + (c*2+1)*Ee;      val = eia + (c*2)*Ee; }
  else if(c < 6){ key = eia + ((c-3)*2)*Ee;    val = eia + ((c-3)*2+1)*Ee; }
  else {          key = fam;                   val = fam + EFf; }
  int pos = atomicAdd(&cursor[c*REG + key[e]], 1);
  ebuf[pos] = val[e];
}

// ---- batched exclusive scan over the 7 concatenated count arrays ----
__global__ void k_scan_p1(const int* __restrict__ cnt, int* __restrict__ part){
  int b = blockIdx.x;
  int base = b*1024 + threadIdx.x*4;
  int s = 0;
  #pragma unroll
  for(int j=0;j<4;j++){ int idx=base+j; if(idx<T7) s += cnt[idx]; }
  __shared__ int red[256];
  red[threadIdx.x]=s; __syncthreads();
  for(int off=128; off>0; off>>=1){
    if(threadIdx.x<off) red[threadIdx.x]+=red[threadIdx.x+off];
    __syncthreads();
  }
  if(threadIdx.x==0) part[b]=red[0];
}

__global__ void k_scan_p2(int* __restrict__ part, int nchunks){
  __shared__ int buf[256];
  int t = threadIdx.x;
  int carry = 0;
  for(int base=0; base<nchunks; base+=256){
    int i = base+t;
    int v = (i<nchunks)? part[i] : 0;
    buf[t]=v; __syncthreads();
    for(int off=1; off<256; off<<=1){
      int add = (t>=off)? buf[t-off] : 0;
      __syncthreads();
      buf[t]+=add; __syncthreads();
    }
    if(i<nchunks) part[i] = carry + buf[t] - v;   // exclusive
    carry += buf[255];
    __syncthreads();
  }
}

__global__ void k_scan_p3(const int* __restrict__ cnt, const int* __restrict__ part,
                          int* __restrict__ offs, int* __restrict__ cursor){
  int b = blockIdx.x;
  int t = threadIdx.x;
  int idx0 = b*1024 + t*4;
  int v[4]; int s=0;
  #pragma unroll
  for(int j=0;j<4;j++){ int idx=idx0+j; v[j] = (idx<T7)? cnt[idx] : 0; s += v[j]; }
  __shared__ int buf[256];
  buf[t]=s; __syncthreads();
  for(int off=1; off<256; off<<=1){
    int add = (t>=off)? buf[t-off] : 0;
    __syncthreads();
    buf[t]+=add; __syncthreads();
  }
  int excl = buf[t] - s + part[b];
  #pragma unroll
  for(int j=0;j<4;j++){
    int idx=idx0+j;
    if(idx<T7){ offs[idx]=excl; cursor[idx]=excl; }
    excl += v[j];
  }
}

// =================== LDS f32 Gauss-Jordan + f64 Newton refinement ===================
// One block per attribute a. W = [A | I] in LDS (128 KB). Partial pivoting.
// After GJ: right half = X0 ~ inv(A) (f32). Newton: E = I - A*X0 (f64 acc),
// X1 = X0 + X0*E (f64 acc). M = X1 + I written f32.
__global__ __launch_bounds__(1024)
void k_gjn(const float* __restrict__ proj, float* __restrict__ Mf32){
  __shared__ float W[128*256];
  __shared__ float pv[128];
  __shared__ float cand_av[2];
  __shared__ float cand_sv[2];
  __shared__ int   cand_ix[2];

  const int a = blockIdx.x;
  const int t = threadIdx.x;
  const int lane = t & 63, wid = t >> 6;
  const float* A = proj + (size_t)a*Dd*Dd;

  // load [A | I]
  for(int idx=t; idx<128*256; idx+=1024){
    int i = idx>>8, c = idx&255;
    float v = (c<128) ? A[(size_t)i*128+c] : ((c-128==i)?1.f:0.f);
    W[idx]=v;
  }
  __syncthreads();

  for(int k=0;k<128;k++){
    // --- pivot search over rows >= k in column k (threads 0..127 = waves 0,1)
    if(t < 128){
      float sv = W[t*256+k];
      float av = (t>=k)? fabsf(sv) : -1.f;
      int ix = t;
      #pragma unroll
      for(int off=32; off; off>>=1){
        float oav = __shfl_xor(av, off);
        float osv = __shfl_xor(sv, off);
        int   oix = __shfl_xor(ix, off);
        if(oav > av){ av=oav; sv=osv; ix=oix; }
      }
      if(lane==0){ cand_av[wid]=av; cand_sv[wid]=sv; cand_ix[wid]=ix; }
    }
    __syncthreads();
    const int   pr     = (cand_av[0] >= cand_av[1]) ? cand_ix[0] : cand_ix[1];
    const float pivinv = 1.f / ((cand_av[0] >= cand_av[1]) ? cand_sv[0] : cand_sv[1]);
    // --- swap rows k<->pr, scale new row k
    if(t < 256){
      int c = t;
      float vk = W[k*256+c];
      float vp = W[pr*256+c];
      W[k*256+c] = ((c==k)?1.f:vp)*pivinv;
      if(pr!=k) W[pr*256+c] = vk;
    }
    __syncthreads();
    // --- stage pivot column (post-swap)
    if(t < 128) pv[t] = W[t*256+k];
    __syncthreads();
    // --- eliminate all rows != k
    {
      int c = t&255, g = t>>8;             // g wave-uniform
      float wk = W[k*256+c];
      #pragma unroll
      for(int m=0;m<32;m++){
        int ll = g + m*4;
        if(ll==k) continue;
        float base = (c==k)? 0.f : W[ll*256+c];
        W[ll*256+c] = fmaf(-pv[ll], wk, base);
      }
    }
    __syncthreads();
  }

  // ---- Newton refinement (f64 accumulate, f32 storage) ----
  // reload A into left half
  for(int idx=t; idx<128*128; idx+=1024){
    int i = idx>>7, c = idx&127;
    W[i*256+c] = A[idx];
  }
  __syncthreads();
  const int i  = t>>3;
  const int j0 = (t&7)*16;
  double acc[16];
  #pragma unroll
  for(int q=0;q<16;q++) acc[q] = (i==j0+q)? 1.0 : 0.0;
  for(int k=0;k<128;k++){
    double aik = (double)W[i*256+k];
    #pragma unroll
    for(int q=0;q<16;q++)
      acc[q] -= aik * (double)W[k*256+128+j0+q];
  }
  __syncthreads();
  // store E (f32) into left half (A dead now)
  #pragma unroll
  for(int q=0;q<16;q++) W[i*256+j0+q] = (float)acc[q];
  __syncthreads();
  // X1 = X0 + X0*E ; M = X1 + I
  #pragma unroll
  for(int q=0;q<16;q++) acc[q] = (double)W[i*256+128+j0+q];
  for(int k=0;k<128;k++){
    double xik = (double)W[i*256+128+k];
    #pragma unroll
    for(int q=0;q<16;q++)
      acc[q] += xik * (double)W[k*256+j0+q];
  }
  float* Mo = Mf32 + (size_t)a*Dd*Dd + (size_t)i*128 + j0;
  #pragma unroll
  for(int q=0;q<16;q++)
    Mo[q] = (float)(acc[q] + ((i==j0+q)? 1.0 : 0.0));
}

// =================== weights-in-registers GEMV/GEMM ===================
// MODE 0: esf  = pos[p,a,:] @ proj[a]                    (W [i,o])
// MODE 1: h    = relu([xattr[a,pop[p]], esf] @ aggW^T+b) (W [o,i], 256 i)
// MODE 2: xatt2= agg1@Wl1^T + xatt1@Wr1^T + b_l1         (dual, [o,i])
// MODE 3: upd  = relu(xatt2[a,pop[p]] @ M[a]), in-place  (W [i,o])
// MODE 4: attO = agg2@Wl2^T + xatt2@Wr2^T + b_l2, in-place over agg2
// MODE 5: indO = agg3@Wl3^T + xind@Wr3^T + b_l3, in-place over agg3
template<int MODE>
__launch_bounds__(256)
__global__ void k_gemm(const float* p1, const float* p2, const float* p3,
                       const float* __restrict__ w1p, const float* __restrict__ w2p,
                       const float* __restrict__ biasp,
                       const int* __restrict__ pop, const int* __restrict__ invpop,
                       float* out, int BPA)
{
  constexpr bool NEEDX2 = (MODE==1 || MODE==2 || MODE==4 || MODE==5);
  const int RPA = (MODE==0||MODE==1||MODE==3) ? Pp : Nn;
  const int a    = (MODE==5) ? 0 : (blockIdx.x / BPA);
  const int bidx = (MODE==5) ? blockIdx.x : (blockIdx.x - a*BPA);

  const int t = threadIdx.x;
  const int wave = t >> 6;
  const int lane = t & 63;
  const int o  = wave*32 + (lane>>1);
  const int ih = lane & 1;            // which half of the i-range this lane covers

  // ---- per-lane weight registers ----
  float4 w1v[16]; float4 w2v[16];
  if constexpr(MODE==0 || MODE==3){
    const float* W = w1p + (size_t)a*Dd*Dd;   // [i][o]
    #pragma unroll
    for(int jj=0;jj<16;jj++){
      int i0 = ih*64 + jj*4;
      float4 v;
      v.x = W[(size_t)(i0+0)*Dd + o];
      v.y = W[(size_t)(i0+1)*Dd + o];
      v.z = W[(size_t)(i0+2)*Dd + o];
      v.w = W[(size_t)(i0+3)*Dd + o];
      w1v[jj]=v;
    }
  } else if constexpr(MODE==1){
    const float* b1 = w1p + (size_t)o*256 + ih*64;       // aggW[o, 0:128]
    const float* b2 = b1 + 128;                          // aggW[o, 128:256]
    #pragma unroll
    for(int jj=0;jj<16;jj++){
      w1v[jj] = reinterpret_cast<const float4*>(b1)[jj];
      w2v[jj] = reinterpret_cast<const float4*>(b2)[jj];
    }
  } else {
    const size_t ao = (MODE==5)? (size_t)0 : (size_t)a*Dd*Dd;
    const float* W1 = w1p + ao + (size_t)o*Dd + ih*64;
    const float* W2 = w2p + ao + (size_t)o*Dd + ih*64;
    #pragma unroll
    for(int jj=0;jj<16;jj++){
      w1v[jj] = reinterpret_cast<const float4*>(W1)[jj];
      w2v[jj] = reinterpret_cast<const float4*>(W2)[jj];
    }
  }
  float bval = 0.f;
  if constexpr(MODE==1 || MODE==5) bval = biasp[o];
  else if constexpr(MODE==2 || MODE==4) bval = biasp[a*Dd + o];

  __shared__ float xs1[RCH][Dd];
  __shared__ float xs2[NEEDX2 ? RCH : 1][Dd];

  const int chunks = (RPA + RCH - 1)/RCH;
  for(int ch = bidx; ch < chunks; ch += BPA){
    const int r0 = ch*RCH;
    const int nr = min(RCH, RPA - r0);
    { // stage rows to LDS (one float4 per thread per stream)
      int r = t >> 5;
      int q = t & 31;
      if(r < nr){
        int row = r0 + r;
        const float* s1 = nullptr; const float* s2 = nullptr;
        if constexpr(MODE==0){ s1 = p1 + ((size_t)row*Aa + a)*Dd; }
        else if constexpr(MODE==1){
          s1 = p1 + ((size_t)a*Nn + pop[row])*Dd;
          s2 = p3 + ((size_t)a*Pp + row)*Dd;
        }
        else if constexpr(MODE==2){
          s1 = p1 + ((size_t)a*Nn + row)*Dd;
          int ip = invpop[row];
          s2 = (ip>=0) ? (p2 + ((size_t)a*Pp + ip)*Dd)
                       : (p3 + ((size_t)a*Nn + row)*Dd);
        }
        else if constexpr(MODE==3){ s1 = p1 + ((size_t)a*Nn + pop[row])*Dd; }
        else if constexpr(MODE==4){
          s1 = p1 + ((size_t)a*Nn + row)*Dd;
          s2 = p3 + ((size_t)a*Nn + row)*Dd;
        }
        else { s1 = p1 + (size_t)row*Dd; s2 = p3 + (size_t)row*Dd; }
        reinterpret_cast<float4*>(xs1[r])[q] = reinterpret_cast<const float4*>(s1)[q];
        if constexpr(NEEDX2)
          reinterpret_cast<float4*>(xs2[r])[q] = reinterpret_cast<const float4*>(s2)[q];
      }
    }
    __syncthreads();
    for(int r=0;r<nr;r++){
      float acc = 0.f;
      const float4* x1 = reinterpret_cast<const float4*>(xs1[r]) + ih*16;
      #pragma unroll
      for(int jj=0;jj<16;jj++){
        float4 xv = x1[jj]; float4 wv = w1v[jj];
        acc = fmaf(xv.x,wv.x,acc); acc = fmaf(xv.y,wv.y,acc);
        acc = fmaf(xv.z,wv.z,acc); acc = fmaf(xv.w,wv.w,acc);
      }
      if constexpr(NEEDX2){
        const float4* x2 = reinterpret_cast<const float4*>(xs2[r]) + ih*16;
        #pragma unroll
        for(int jj=0;jj<16;jj++){
          float4 xv = x2[jj]; float4 wv = w2v[jj];
          acc = fmaf(xv.x,wv.x,acc); acc = fmaf(xv.y,wv.y,acc);
          acc = fmaf(xv.z,wv.z,acc); acc = fmaf(xv.w,wv.w,acc);
        }
      }
      acc += __shfl_xor(acc, 1, 64);
      if(ih==0){
        float vout = acc;
        if constexpr(MODE==1 || MODE==2 || MODE==4 || MODE==5) vout += bval;
        if constexpr(MODE==1 || MODE==3) vout = fmaxf(vout, 0.f);
        int row = r0 + r;
        size_t orow;
        if constexpr(MODE==0)      orow = (size_t)a*Pp + row;
        else if constexpr(MODE==1) orow = (size_t)a*Pp + row;
        else if constexpr(MODE==2) orow = (size_t)a*Nn + row;
        else if constexpr(MODE==3) orow = (size_t)a*Nn + pop[row];
        else if constexpr(MODE==4) orow = (size_t)a*Nn + row;
        else                       orow = (size_t)row;
        out[orow*Dd + o] = vout;
      }
    }
    __syncthreads();
  }
}

// =================== CSR gather segment-mean (one wave per row) ===================
// WHICH 0: agg1 (src=x_individuals, regions 0..2, dst per-a)
// WHICH 1: agg2 (src=xatt2 per-a, regions 3..5, dst per-a)
// WHICH 2: agg3 (src=x_individuals, region 6, dst single)
template<int WHICH>
__global__ void k_seg(const float* __restrict__ src, const int* __restrict__ offs,
                      const int* __restrict__ ebuf, float* __restrict__ dst)
{
  const int nw = gridDim.x * 4;              // 256 threads = 4 waves per block
  int gw = (blockIdx.x*256 + threadIdx.x) >> 6;
  const int lane = threadIdx.x & 63;
  const int ROWS = (WHICH==2) ? Nn : Aa*Nn;
  const int cbase = (WHICH==0)?0 : (WHICH==1)?3 : 6;
  for(int row = gw; row < ROWS; row += nw){
    int aa = (WHICH==2)? 0   : row / Nn;
    int n  = (WHICH==2)? row : row - aa*Nn;
    const int* op = offs + (size_t)(cbase+aa)*REG + n;
    int s = op[0], e = op[1];
    float a0=0.f, a1=0.f;
    for(int j=s;j<e;++j){
      int v = ebuf[j];
      const float* rp = src + ((WHICH==1)? ((size_t)aa*Nn+v) : (size_t)v)*Dd;
      a0 += rp[lane]; a1 += rp[lane+64];
    }
    float sc = (e>s)? 1.f/(float)(e-s) : 0.f;
    float* dp = dst + ((WHICH==2)? (size_t)n : ((size_t)aa*Nn+n))*Dd;
    dp[lane]      = a0*sc;
    dp[lane+64]   = a1*sc;
  }
}

// =================== launch ===================
extern "C" void kernel_launch(void* const* d_in, const int* in_sizes, int n_in,
                              void* d_out, int out_size, void* d_ws, size_t ws_size,
                              hipStream_t stream)
{
  const float* xind  = (const float*)d_in[0];
  const float* xattr = (const float*)d_in[1];
  const float* posf  = (const float*)d_in[2];
  const int*   pop   = (const int*)  d_in[3];
  const int*   eia   = (const int*)  d_in[4];
  const int*   fam   = (const int*)  d_in[5];
  const float* proj  = (const float*)d_in[6];
  const float* aggW  = (const float*)d_in[7];
  const float* aggb  = (const float*)d_in[8];
  const float* Wl1   = (const float*)d_in[9];
  const float* bl1   = (const float*)d_in[10];
  const float* Wr1   = (const float*)d_in[11];
  const float* Wl2   = (const float*)d_in[12];
  const float* bl2   = (const float*)d_in[13];
  const float* Wr2   = (const float*)d_in[14];
  const float* Wl3   = (const float*)d_in[15];
  const float* bl3   = (const float*)d_in[16];
  const float* Wr3   = (const float*)d_in[17];

  float* outind = (float*)d_out;                     // (N,D)
  float* outatt = outind + (size_t)Nn*Dd;            // (A,N,D)

  // ---- workspace carve-up ----
  float* h_buf   = (float*)d_ws;                         // A*P*D
  float* esf_buf = h_buf   + (size_t)Aa*Pp*Dd;           // A*P*D
  float* xatt2   = esf_buf + (size_t)Aa*Pp*Dd;           // A*N*D
  int*   ebuf    = (int*)(xatt2 + (size_t)Aa*Nn*Dd);     // 7E
  int*   cnt     = ebuf   + (size_t)NCSR*Ee;             // 700008 (padded)
  int*   offs    = cnt    + 700008;
  int*   cursor  = offs   + 700008;
  int*   part    = cursor + 700008;                      // 1024
  int*   invpop  = part   + 1024;                        // N
  float* Mf32    = (float*)(invpop + Nn);                // A*128*128

  hipMemsetAsync(cnt,    0,    sizeof(int)*700008, stream);
  hipMemsetAsync(invpop, 0xFF, sizeof(int)*Nn,     stream);

  k_invpop<<<(Pp+255)/256, 256, 0, stream>>>(pop, invpop);
  const int egrid = (NCSR*Ee + 255)/256;
  k_count<<<egrid, 256, 0, stream>>>(eia, fam, cnt);
  const int nchunks = (T7 + 1023)/1024;   // 684
  k_scan_p1<<<nchunks, 256, 0, stream>>>(cnt, part);
  k_scan_p2<<<1, 256, 0, stream>>>(part, nchunks);
  k_scan_p3<<<nchunks, 256, 0, stream>>>(cnt, part, offs, cursor);
  k_fill<<<egrid, 256, 0, stream>>>(eia, fam, cursor, ebuf);

  // M = inv(proj) + I  (LDS f32 GJ + f64 Newton)
  k_gjn<<<Aa, 1024, 0, stream>>>(proj, Mf32);

  const int BPA = 240;
  // esf = pos @ proj
  k_gemm<0><<<Aa*BPA, 256, 0, stream>>>(posf, nullptr, nullptr,
                                        proj, nullptr, nullptr,
                                        pop, invpop, esf_buf, BPA);
  // h = relu([xattr[:,pop,:], esf] @ aggW^T + b)
  k_gemm<1><<<Aa*BPA, 256, 0, stream>>>(xattr, nullptr, esf_buf,
                                        aggW, nullptr, aggb,
                                        pop, invpop, h_buf, BPA);
  // agg1 -> outatt
  k_seg<0><<<1024, 256, 0, stream>>>(xind, offs, ebuf, outatt);
  // xatt2 = agg1@Wl1^T + xatt1@Wr1^T + b_l1   (xatt1 = xattr w/ pop rows = h)
  k_gemm<2><<<Aa*BPA, 256, 0, stream>>>(outatt, h_buf, xattr,
                                        Wl1, Wr1, bl1,
                                        pop, invpop, xatt2, BPA);
  // upd = relu(xatt2[:,pop,:] @ M), in place
  k_gemm<3><<<Aa*BPA, 256, 0, stream>>>(xatt2, nullptr, nullptr,
                                        Mf32, nullptr, nullptr,
                                        pop, invpop, xatt2, BPA);
  // agg2 -> outatt (overwrites agg1, which is dead)
  k_seg<1><<<1024, 256, 0, stream>>>(xatt2, offs, ebuf, outatt);
  // x_att_out = agg2@Wl2^T + xatt2@Wr2^T + b_l2, in place over agg2
  k_gemm<4><<<Aa*BPA, 256, 0, stream>>>(outatt, nullptr, xatt2,
                                        Wl2, Wr2, bl2,
                                        pop, invpop, outatt, BPA);
  // agg3 -> outind
  k_seg<2><<<1024, 256, 0, stream>>>(xind, offs, ebuf, outind);
  // x_ind_out = agg3@Wl3^T + xind@Wr3^T + b_l3, in place over agg3
  k_gemm<5><<<Aa*BPA, 256, 0, stream>>>(outind, nullptr, xind,
                                        Wl3, Wr3, bl3,
                                        pop, invpop, outind, Aa*BPA);
}

// Round 3
// 3718.102 us; speedup vs baseline: 1.6463x; 1.0352x over previous
//
#include <hip/hip_runtime.h>
#include <cstddef>

// ---- problem constants ----
constexpr int Nn  = 100000;
constexpr int Dd  = 128;
constexpr int Aa  = 3;
constexpr int Pp  = 50000;
constexpr int Ee  = 500000;
constexpr int EFf = 500000;
constexpr int REG = Nn + 1;        // 100001 (count slots per CSR, incl. pad)
constexpr int NCSR = 7;            // 3x agg1(dst), 3x agg2(src), 1x family
constexpr int T7  = NCSR * REG;    // 700007
constexpr int RCH = 8;             // rows per LDS chunk in GEMM kernels

// =================== CSR build ===================
__global__ void k_invpop(const int* __restrict__ pop, int* __restrict__ invpop){
  int p = blockIdx.x*256 + threadIdx.x;
  if(p < Pp) invpop[pop[p]] = p;
}

__global__ void k_count(const int* __restrict__ eia, const int* __restrict__ fam,
                        int* __restrict__ cnt){
  int tid = blockIdx.x*256 + threadIdx.x;
  if(tid >= NCSR*Ee) return;
  int c = tid / Ee, e = tid - c*Ee;
  const int* key;
  if(c < 3)       key = eia + (c*2+1)*Ee;        // agg1: segment by dst
  else if(c < 6)  key = eia + ((c-3)*2)*Ee;      // agg2: segment by src
  else            key = fam;                      // agg3: segment by fam[0]
  atomicAdd(&cnt[c*REG + key[e]], 1);
}

__global__ void k_fill(const int* __restrict__ eia, const int* __restrict__ fam,
                       int* __restrict__ cursor, int* __restrict__ ebuf){
  int tid = blockIdx.x*256 + threadIdx.x;
  if(tid >= NCSR*Ee) return;
  int c = tid / Ee, e = tid - c*Ee;
  const int *key, *val;
  if(c < 3){      key = eia + (c*2+1)*Ee;      val = eia + (c*2)*Ee; }
  else if(c < 6){ key = eia + ((c-3)*2)*Ee;    val = eia + ((c-3)*2+1)*Ee; }
  else {          key = fam;                   val = fam + EFf; }
  int pos = atomicAdd(&cursor[c*REG + key[e]], 1);
  ebuf[pos] = val[e];
}

// ---- batched exclusive scan over the 7 concatenated count arrays ----
__global__ void k_scan_p1(const int* __restrict__ cnt, int* __restrict__ part){
  int b = blockIdx.x;
  int base = b*1024 + threadIdx.x*4;
  int s = 0;
  #pragma unroll
  for(int j=0;j<4;j++){ int idx=base+j; if(idx<T7) s += cnt[idx]; }
  __shared__ int red[256];
  red[threadIdx.x]=s; __syncthreads();
  for(int off=128; off>0; off>>=1){
    if(threadIdx.x<off) red[threadIdx.x]+=red[threadIdx.x+off];
    __syncthreads();
  }
  if(threadIdx.x==0) part[b]=red[0];
}

__global__ void k_scan_p2(int* __restrict__ part, int nchunks){
  __shared__ int buf[256];
  int t = threadIdx.x;
  int carry = 0;
  for(int base=0; base<nchunks; base+=256){
    int i = base+t;
    int v = (i<nchunks)? part[i] : 0;
    buf[t]=v; __syncthreads();
    for(int off=1; off<256; off<<=1){
      int add = (t>=off)? buf[t-off] : 0;
      __syncthreads();
      buf[t]+=add; __syncthreads();
    }
    if(i<nchunks) part[i] = carry + buf[t] - v;   // exclusive
    carry += buf[255];
    __syncthreads();
  }
}

__global__ void k_scan_p3(const int* __restrict__ cnt, const int* __restrict__ part,
                          int* __restrict__ offs, int* __restrict__ cursor){
  int b = blockIdx.x;
  int t = threadIdx.x;
  int idx0 = b*1024 + t*4;
  int v[4]; int s=0;
  #pragma unroll
  for(int j=0;j<4;j++){ int idx=idx0+j; v[j] = (idx<T7)? cnt[idx] : 0; s += v[j]; }
  __shared__ int buf[256];
  buf[t]=s; __syncthreads();
  for(int off=1; off<256; off<<=1){
    int add = (t>=off)? buf[t-off] : 0;
    __syncthreads();
    buf[t]+=add; __syncthreads();
  }
  int excl = buf[t] - s + part[b];
  #pragma unroll
  for(int j=0;j<4;j++){
    int idx=idx0+j;
    if(idx<T7){ offs[idx]=excl; cursor[idx]=excl; }
    excl += v[j];
  }
}

// =================== LDS f32 Gauss-Jordan + f64 Newton refinement ===================
__global__ __launch_bounds__(1024)
void k_gjn(const float* __restrict__ proj, float* __restrict__ Mf32){
  __shared__ float W[128*256];
  __shared__ float pv[128];
  __shared__ float cand_av[2];
  __shared__ float cand_sv[2];
  __shared__ int   cand_ix[2];

  const int a = blockIdx.x;
  const int t = threadIdx.x;
  const int lane = t & 63, wid = t >> 6;
  const float* A = proj + (size_t)a*Dd*Dd;

  for(int idx=t; idx<128*256; idx+=1024){
    int i = idx>>8, c = idx&255;
    float v = (c<128) ? A[(size_t)i*128+c] : ((c-128==i)?1.f:0.f);
    W[idx]=v;
  }
  __syncthreads();

  for(int k=0;k<128;k++){
    if(t < 128){
      float sv = W[t*256+k];
      float av = (t>=k)? fabsf(sv) : -1.f;
      int ix = t;
      #pragma unroll
      for(int off=32; off; off>>=1){
        float oav = __shfl_xor(av, off);
        float osv = __shfl_xor(sv, off);
        int   oix = __shfl_xor(ix, off);
        if(oav > av){ av=oav; sv=osv; ix=oix; }
      }
      if(lane==0){ cand_av[wid]=av; cand_sv[wid]=sv; cand_ix[wid]=ix; }
    }
    __syncthreads();
    const int   pr     = (cand_av[0] >= cand_av[1]) ? cand_ix[0] : cand_ix[1];
    const float pivinv = 1.f / ((cand_av[0] >= cand_av[1]) ? cand_sv[0] : cand_sv[1]);
    if(t < 256){
      int c = t;
      float vk = W[k*256+c];
      float vp = W[pr*256+c];
      W[k*256+c] = ((c==k)?1.f:vp)*pivinv;
      if(pr!=k) W[pr*256+c] = vk;
    }
    __syncthreads();
    if(t < 128) pv[t] = W[t*256+k];
    __syncthreads();
    {
      int c = t&255, g = t>>8;
      float wk = W[k*256+c];
      #pragma unroll
      for(int m=0;m<32;m++){
        int ll = g + m*4;
        if(ll==k) continue;
        float base = (c==k)? 0.f : W[ll*256+c];
        W[ll*256+c] = fmaf(-pv[ll], wk, base);
      }
    }
    __syncthreads();
  }

  for(int idx=t; idx<128*128; idx+=1024){
    int i = idx>>7, c = idx&127;
    W[i*256+c] = A[idx];
  }
  __syncthreads();
  const int i  = t>>3;
  const int j0 = (t&7)*16;
  double acc[16];
  #pragma unroll
  for(int q=0;q<16;q++) acc[q] = (i==j0+q)? 1.0 : 0.0;
  for(int k=0;k<128;k++){
    double aik = (double)W[i*256+k];
    #pragma unroll
    for(int q=0;q<16;q++)
      acc[q] -= aik * (double)W[k*256+128+j0+q];
  }
  __syncthreads();
  #pragma unroll
  for(int q=0;q<16;q++) W[i*256+j0+q] = (float)acc[q];
  __syncthreads();
  #pragma unroll
  for(int q=0;q<16;q++) acc[q] = (double)W[i*256+128+j0+q];
  for(int k=0;k<128;k++){
    double xik = (double)W[i*256+128+k];
    #pragma unroll
    for(int q=0;q<16;q++)
      acc[q] += xik * (double)W[k*256+j0+q];
  }
  float* Mo = Mf32 + (size_t)a*Dd*Dd + (size_t)i*128 + j0;
  #pragma unroll
  for(int q=0;q<16;q++)
    Mo[q] = (float)(acc[q] + ((i==j0+q)? 1.0 : 0.0));
}

// =================== weights-in-registers GEMV/GEMM ===================
// Ping-pong LDS (1 barrier/chunk) + register prefetch of next chunk (T14).
// MODE 0: esf  = pos[p,a,:] @ proj[a]                    (W [i,o])
// MODE 1: h    = relu([xattr[a,pop[p]], esf] @ aggW^T+b) (W [o,i], 256 i)
// MODE 2: xatt2= agg1@Wl1^T + xatt1@Wr1^T + b_l1         (dual, [o,i])
// MODE 3: upd  = relu(xatt2[a,pop[p]] @ M[a]), in-place  (W [i,o])
// MODE 4: attO = agg2@Wl2^T + xatt2@Wr2^T + b_l2, in-place over agg2
// MODE 5: indO = agg3@Wl3^T + xind@Wr3^T + b_l3, in-place over agg3
template<int MODE>
__launch_bounds__(256)
__global__ void k_gemm(const float* p1, const float* p2, const float* p3,
                       const float* __restrict__ w1p, const float* __restrict__ w2p,
                       const float* __restrict__ biasp,
                       const int* __restrict__ pop, const int* __restrict__ invpop,
                       float* out, int BPA)
{
  constexpr bool NEEDX2 = (MODE==1 || MODE==2 || MODE==4 || MODE==5);
  const int RPA = (MODE==0||MODE==1||MODE==3) ? Pp : Nn;
  const int a    = (MODE==5) ? 0 : (blockIdx.x / BPA);
  const int bidx = (MODE==5) ? blockIdx.x : (blockIdx.x - a*BPA);

  const int t = threadIdx.x;
  const int wave = t >> 6;
  const int lane = t & 63;
  const int o  = wave*32 + (lane>>1);
  const int ih = lane & 1;            // which half of the i-range this lane covers

  // ---- per-lane weight registers ----
  float4 w1v[16]; float4 w2v[16];
  if constexpr(MODE==0 || MODE==3){
    const float* W = w1p + (size_t)a*Dd*Dd;   // [i][o]
    #pragma unroll
    for(int jj=0;jj<16;jj++){
      int i0 = ih*64 + jj*4;
      float4 v;
      v.x = W[(size_t)(i0+0)*Dd + o];
      v.y = W[(size_t)(i0+1)*Dd + o];
      v.z = W[(size_t)(i0+2)*Dd + o];
      v.w = W[(size_t)(i0+3)*Dd + o];
      w1v[jj]=v;
    }
  } else if constexpr(MODE==1){
    const float* b1 = w1p + (size_t)o*256 + ih*64;       // aggW[o, 0:128]
    const float* b2 = b1 + 128;                          // aggW[o, 128:256]
    #pragma unroll
    for(int jj=0;jj<16;jj++){
      w1v[jj] = reinterpret_cast<const float4*>(b1)[jj];
      w2v[jj] = reinterpret_cast<const float4*>(b2)[jj];
    }
  } else {
    const size_t ao = (MODE==5)? (size_t)0 : (size_t)a*Dd*Dd;
    const float* W1 = w1p + ao + (size_t)o*Dd + ih*64;
    const float* W2 = w2p + ao + (size_t)o*Dd + ih*64;
    #pragma unroll
    for(int jj=0;jj<16;jj++){
      w1v[jj] = reinterpret_cast<const float4*>(W1)[jj];
      w2v[jj] = reinterpret_cast<const float4*>(W2)[jj];
    }
  }
  float bval = 0.f;
  if constexpr(MODE==1 || MODE==5) bval = biasp[o];
  else if constexpr(MODE==2 || MODE==4) bval = biasp[a*Dd + o];

  __shared__ float xs1[2][RCH][Dd];
  __shared__ float xs2[2][NEEDX2 ? RCH : 1][Dd];

  const int chunks = (RPA + RCH - 1)/RCH;
  const int r = t >> 5;    // staging row 0..7
  const int q = t & 31;    // staging float4 index

  float4 pre1 = {0,0,0,0}, pre2 = {0,0,0,0};
  auto prefetch = [&](int chp){
    if(chp >= chunks) return;
    if(r >= RPA - chp*RCH) return;
    int row = chp*RCH + r;
    const float* s1 = nullptr; const float* s2 = nullptr;
    if constexpr(MODE==0){ s1 = p1 + ((size_t)row*Aa + a)*Dd; }
    else if constexpr(MODE==1){
      s1 = p1 + ((size_t)a*Nn + pop[row])*Dd;
      s2 = p3 + ((size_t)a*Pp + row)*Dd;
    }
    else if constexpr(MODE==2){
      s1 = p1 + ((size_t)a*Nn + row)*Dd;
      int ip = invpop[row];
      s2 = (ip>=0) ? (p2 + ((size_t)a*Pp + ip)*Dd)
                   : (p3 + ((size_t)a*Nn + row)*Dd);
    }
    else if constexpr(MODE==3){ s1 = p1 + ((size_t)a*Nn + pop[row])*Dd; }
    else if constexpr(MODE==4){
      s1 = p1 + ((size_t)a*Nn + row)*Dd;
      s2 = p3 + ((size_t)a*Nn + row)*Dd;
    }
    else { s1 = p1 + (size_t)row*Dd; s2 = p3 + (size_t)row*Dd; }
    pre1 = reinterpret_cast<const float4*>(s1)[q];
    if constexpr(NEEDX2) pre2 = reinterpret_cast<const float4*>(s2)[q];
  };

  prefetch(bidx);
  int buf = 0;
  for(int ch = bidx; ch < chunks; ch += BPA){
    const int nr = min(RCH, RPA - ch*RCH);
    if(r < nr){
      reinterpret_cast<float4*>(xs1[buf][r])[q] = pre1;
      if constexpr(NEEDX2)
        reinterpret_cast<float4*>(xs2[buf][r])[q] = pre2;
    }
    __syncthreads();               // writes to buf visible; prev compute (buf^1) done
    prefetch(ch + BPA);            // issue next-chunk gathers early (hidden under FMA)
    for(int rr=0; rr<nr; rr++){
      float acc = 0.f;
      const float4* x1 = reinterpret_cast<const float4*>(xs1[buf][rr]) + ih*16;
      #pragma unroll
      for(int jj=0;jj<16;jj++){
        float4 xv = x1[jj]; float4 wv = w1v[jj];
        acc = fmaf(xv.x,wv.x,acc); acc = fmaf(xv.y,wv.y,acc);
        acc = fmaf(xv.z,wv.z,acc); acc = fmaf(xv.w,wv.w,acc);
      }
      if constexpr(NEEDX2){
        const float4* x2 = reinterpret_cast<const float4*>(xs2[buf][rr]) + ih*16;
        #pragma unroll
        for(int jj=0;jj<16;jj++){
          float4 xv = x2[jj]; float4 wv = w2v[jj];
          acc = fmaf(xv.x,wv.x,acc); acc = fmaf(xv.y,wv.y,acc);
          acc = fmaf(xv.z,wv.z,acc); acc = fmaf(xv.w,wv.w,acc);
        }
      }
      acc += __shfl_xor(acc, 1, 64);
      if(ih==0){
        float vout = acc;
        if constexpr(MODE==1 || MODE==2 || MODE==4 || MODE==5) vout += bval;
        if constexpr(MODE==1 || MODE==3) vout = fmaxf(vout, 0.f);
        int row = ch*RCH + rr;
        size_t orow;
        if constexpr(MODE==0)      orow = (size_t)a*Pp + row;
        else if constexpr(MODE==1) orow = (size_t)a*Pp + row;
        else if constexpr(MODE==2) orow = (size_t)a*Nn + row;
        else if constexpr(MODE==3) orow = (size_t)a*Nn + pop[row];
        else if constexpr(MODE==4) orow = (size_t)a*Nn + row;
        else                       orow = (size_t)row;
        out[orow*Dd + o] = vout;
      }
    }
    buf ^= 1;
  }
}

// =================== CSR gather segment-mean (one wave per row) ===================
template<int WHICH>
__global__ void k_seg(const float* __restrict__ src, const int* __restrict__ offs,
                      const int* __restrict__ ebuf, float* __restrict__ dst)
{
  const int nw = gridDim.x * 4;              // 256 threads = 4 waves per block
  int gw = (blockIdx.x*256 + threadIdx.x) >> 6;
  const int lane = threadIdx.x & 63;
  const int ROWS = (WHICH==2) ? Nn : Aa*Nn;
  const int cbase = (WHICH==0)?0 : (WHICH==1)?3 : 6;
  for(int row = gw; row < ROWS; row += nw){
    int aa = (WHICH==2)? 0   : row / Nn;
    int n  = (WHICH==2)? row : row - aa*Nn;
    const int* op = offs + (size_t)(cbase+aa)*REG + n;
    int s = op[0], e = op[1];
    float a0=0.f, a1=0.f;
    for(int j=s;j<e;++j){
      int v = ebuf[j];
      const float* rp = src + ((WHICH==1)? ((size_t)aa*Nn+v) : (size_t)v)*Dd;
      a0 += rp[lane]; a1 += rp[lane+64];
    }
    float sc = (e>s)? 1.f/(float)(e-s) : 0.f;
    float* dp = dst + ((WHICH==2)? (size_t)n : ((size_t)aa*Nn+n))*Dd;
    dp[lane]      = a0*sc;
    dp[lane+64]   = a1*sc;
  }
}

// =================== launch ===================
extern "C" void kernel_launch(void* const* d_in, const int* in_sizes, int n_in,
                              void* d_out, int out_size, void* d_ws, size_t ws_size,
                              hipStream_t stream)
{
  const float* xind  = (const float*)d_in[0];
  const float* xattr = (const float*)d_in[1];
  const float* posf  = (const float*)d_in[2];
  const int*   pop   = (const int*)  d_in[3];
  const int*   eia   = (const int*)  d_in[4];
  const int*   fam   = (const int*)  d_in[5];
  const float* proj  = (const float*)d_in[6];
  const float* aggW  = (const float*)d_in[7];
  const float* aggb  = (const float*)d_in[8];
  const float* Wl1   = (const float*)d_in[9];
  const float* bl1   = (const float*)d_in[10];
  const float* Wr1   = (const float*)d_in[11];
  const float* Wl2   = (const float*)d_in[12];
  const float* bl2   = (const float*)d_in[13];
  const float* Wr2   = (const float*)d_in[14];
  const float* Wl3   = (const float*)d_in[15];
  const float* bl3   = (const float*)d_in[16];
  const float* Wr3   = (const float*)d_in[17];

  float* outind = (float*)d_out;                     // (N,D)
  float* outatt = outind + (size_t)Nn*Dd;            // (A,N,D)

  // ---- workspace carve-up ----
  float* h_buf   = (float*)d_ws;                         // A*P*D
  float* esf_buf = h_buf   + (size_t)Aa*Pp*Dd;           // A*P*D
  float* xatt2   = esf_buf + (size_t)Aa*Pp*Dd;           // A*N*D
  int*   ebuf    = (int*)(xatt2 + (size_t)Aa*Nn*Dd);     // 7E
  int*   cnt     = ebuf   + (size_t)NCSR*Ee;             // 700008 (padded)
  int*   offs    = cnt    + 700008;
  int*   cursor  = offs   + 700008;
  int*   part    = cursor + 700008;                      // 1024
  int*   invpop  = part   + 1024;                        // N
  float* Mf32    = (float*)(invpop + Nn);                // A*128*128

  hipMemsetAsync(cnt,    0,    sizeof(int)*700008, stream);
  hipMemsetAsync(invpop, 0xFF, sizeof(int)*Nn,     stream);

  k_invpop<<<(Pp+255)/256, 256, 0, stream>>>(pop, invpop);
  const int egrid = (NCSR*Ee + 255)/256;
  k_count<<<egrid, 256, 0, stream>>>(eia, fam, cnt);
  const int nchunks = (T7 + 1023)/1024;   // 684
  k_scan_p1<<<nchunks, 256, 0, stream>>>(cnt, part);
  k_scan_p2<<<1, 256, 0, stream>>>(part, nchunks);
  k_scan_p3<<<nchunks, 256, 0, stream>>>(cnt, part, offs, cursor);
  k_fill<<<egrid, 256, 0, stream>>>(eia, fam, cursor, ebuf);

  // M = inv(proj) + I  (LDS f32 GJ + f64 Newton)
  k_gjn<<<Aa, 1024, 0, stream>>>(proj, Mf32);

  const int BPA = 960;
  // esf = pos @ proj
  k_gemm<0><<<Aa*BPA, 256, 0, stream>>>(posf, nullptr, nullptr,
                                        proj, nullptr, nullptr,
                                        pop, invpop, esf_buf, BPA);
  // h = relu([xattr[:,pop,:], esf] @ aggW^T + b)
  k_gemm<1><<<Aa*BPA, 256, 0, stream>>>(xattr, nullptr, esf_buf,
                                        aggW, nullptr, aggb,
                                        pop, invpop, h_buf, BPA);
  // agg1 -> outatt
  k_seg<0><<<2048, 256, 0, stream>>>(xind, offs, ebuf, outatt);
  // xatt2 = agg1@Wl1^T + xatt1@Wr1^T + b_l1   (xatt1 = xattr w/ pop rows = h)
  k_gemm<2><<<Aa*BPA, 256, 0, stream>>>(outatt, h_buf, xattr,
                                        Wl1, Wr1, bl1,
                                        pop, invpop, xatt2, BPA);
  // upd = relu(xatt2[:,pop,:] @ M), in place
  k_gemm<3><<<Aa*BPA, 256, 0, stream>>>(xatt2, nullptr, nullptr,
                                        Mf32, nullptr, nullptr,
                                        pop, invpop, xatt2, BPA);
  // agg2 -> outatt (overwrites agg1, which is dead)
  k_seg<1><<<2048, 256, 0, stream>>>(xatt2, offs, ebuf, outatt);
  // x_att_out = agg2@Wl2^T + xatt2@Wr2^T + b_l2, in place over agg2
  k_gemm<4><<<Aa*BPA, 256, 0, stream>>>(outatt, nullptr, xatt2,
                                        Wl2, Wr2, bl2,
                                        pop, invpop, outatt, BPA);
  // agg3 -> outind
  k_seg<2><<<2048, 256, 0, stream>>>(xind, offs, ebuf, outind);
  // x_ind_out = agg3@Wl3^T + xind@Wr3^T + b_l3, in place over agg3
  k_gemm<5><<<Aa*BPA, 256, 0, stream>>>(outind, nullptr, xind,
                                        Wl3, Wr3, bl3,
                                        pop, invpop, outind, Aa*BPA);
}